// Round 8
// baseline (110.568 us; speedup 1.0000x reference)
//
#include <hip/hip_runtime.h>

#define NUM_CP 64
#define D_MODEL 128
#define RPB_MAX 512   // max rows per block staged in LDS (2 KB)

typedef float f32x4 __attribute__((ext_vector_type(4)));

// Exact algebraic collapse of the reference for t in [0,1]:
//   out[n][d] = B[d] + clip(t[n],0,1) * C[d]
//   B[d] = sum_{i=0}^{62} (1 - i) * cp[i][d]
//   C[d] = -cp[0][d] + sum_{i=1}^{62} cp[i][d]
//
// R8 structure: block-contiguous row partitioning. Each block stages its
// whole t-slab (<=2 KB) into LDS in one coalesced burst, then the steady
// loop is PURE nontemporal stores (t from LDS -> lgkmcnt; no vmcnt reads
// interleaved with the write stream, no HBM R/W turnaround per 4 KB, and
// each block writes one sequential 250 KB stream for row-buffer locality).
__global__ __launch_bounds__(256) void spline_fused(const float* __restrict__ t,
                                                    const float* __restrict__ cp,
                                                    float* __restrict__ out,
                                                    int n, int rpb) {
    __shared__ float sbc[2 * D_MODEL];
    __shared__ float st[RPB_MAX];

    const int tid = threadIdx.x;

    // ---- per-block coefficient reduction (threads 0-127, f32, ~63 L1 loads) ----
    if (tid < D_MODEL) {
        float v0 = cp[tid];            // cp[0][d]
        float B = v0, C = -v0;
        for (int i = 1; i < NUM_CP - 1; ++i) {
            float v = cp[i * D_MODEL + tid];
            B = fmaf(1.0f - (float)i, v, B);
            C += v;
        }
        sbc[tid] = B;
        sbc[D_MODEL + tid] = C;
    }

    // ---- stage this block's t slab into LDS (one burst) ----
    const int base = blockIdx.x * rpb;           // rpb % 8 == 0 -> 16B-aligned
    const int cnt  = min(rpb, n - base);         // grid sized so cnt > 0
    {
        const f32x4* tq = reinterpret_cast<const f32x4*>(t + base);
        const int quads = cnt >> 2;
        for (int q = tid; q < quads; q += 256)
            reinterpret_cast<f32x4*>(st)[q] = tq[q];
        for (int r = (quads << 2) + tid; r < cnt; r += 256)
            st[r] = t[base + r];
    }
    __syncthreads();

    const int lane = tid & 63;
    const int c    = lane & 31;        // float4 column (0..31) -> dims 4c..4c+3
    const int half = lane >> 5;        // 0 or 1
    const int wave = tid >> 6;

    const f32x4 b  = reinterpret_cast<const f32x4*>(sbc)[c];
    const f32x4 cv = reinterpret_cast<const f32x4*>(sbc + D_MODEL)[c];
    f32x4* __restrict__ outq = reinterpret_cast<f32x4*>(out) + (size_t)base * (D_MODEL / 4);

    // Wave layout per 8-row chunk: lanes 0-31 -> rows r0..r0+3 (lane = float4
    // column c), lanes 32-63 -> rows r0+4..r0+7. 16 FMAs + 4 NT stores/thread.
    for (int r0 = wave * 8; r0 < cnt; r0 += 32) {
        const int r = r0 + half * 4;   // this thread's 4 local rows: r..r+3
        if (r0 + 7 < cnt) {
            const f32x4 t4 = reinterpret_cast<const f32x4*>(st)[r >> 2];  // LDS broadcast
            float tv[4];
#pragma unroll
            for (int k = 0; k < 4; ++k) tv[k] = fminf(fmaxf(t4[k], 0.0f), 1.0f);
#pragma unroll
            for (int k = 0; k < 4; ++k) {
                f32x4 o;
                o.x = fmaf(tv[k], cv.x, b.x);
                o.y = fmaf(tv[k], cv.y, b.y);
                o.z = fmaf(tv[k], cv.z, b.z);
                o.w = fmaf(tv[k], cv.w, b.w);
                __builtin_nontemporal_store(o, &outq[(r + k) * (D_MODEL / 4) + c]);
            }
        } else {
            for (int k = 0; k < 4; ++k) {
                const int rr = r + k;
                if (rr < cnt) {
                    const float tv = fminf(fmaxf(st[rr], 0.0f), 1.0f);
                    f32x4 o;
                    o.x = fmaf(tv, cv.x, b.x);
                    o.y = fmaf(tv, cv.y, b.y);
                    o.z = fmaf(tv, cv.z, b.z);
                    o.w = fmaf(tv, cv.w, b.w);
                    __builtin_nontemporal_store(o, &outq[rr * (D_MODEL / 4) + c]);
                }
            }
        }
    }
}

extern "C" void kernel_launch(void* const* d_in, const int* in_sizes, int n_in,
                              void* d_out, int out_size, void* d_ws, size_t ws_size,
                              hipStream_t stream) {
    const float* t  = (const float*)d_in[0];
    const float* cp = (const float*)d_in[1];
    float* out = (float*)d_out;
    const int n = in_sizes[0];

    // Target ~2048 blocks; rows-per-block rounded to a multiple of 8 (and
    // capped by the LDS slab). n = 1e6 -> rpb = 496, blocks = 2017.
    int rpb = ((n + 2048 * 8 - 1) / (2048 * 8)) * 8;
    if (rpb > RPB_MAX) rpb = RPB_MAX;
    if (rpb < 8) rpb = 8;
    const int blocks = (n + rpb - 1) / rpb;
    spline_fused<<<blocks, 256, 0, stream>>>(t, cp, out, n, rpb);
}

// Round 9
// 102.226 us; speedup vs baseline: 1.0816x; 1.0816x over previous
//
#include <hip/hip_runtime.h>

#define NUM_CP 64
#define D_MODEL 128

typedef float f32x4 __attribute__((ext_vector_type(4)));

// Exact algebraic collapse of the reference for t in [0,1]:
//   out[n][d] = B[d] + clip(t[n],0,1) * C[d]
//   B[d] = sum_{i=0}^{62} (1 - i) * cp[i][d]
//   C[d] = -cp[0][d] + sum_{i=1}^{62} cp[i][d]
//
// R9: store layout changed so EVERY wave store is one contiguous 1 KB
// segment (lane l writes base + l*16), matching the 6.9 TB/s fill kernel.
// Store k covers the consecutive row pair (r0+2k, r0+2k+1): lanes 0-31 ->
// even row (col c), lanes 32-63 -> odd row. Previous layout wrote two
// 512 B segments 2 KB apart per instruction (suspected TA segment-split
// cost ~25 us across 2.1M wave-stores). t comes from two broadcast 16 B
// loads + 4 wave-uniform selects. NT stores + pipelined prefetch retained.
__global__ __launch_bounds__(256) void spline_fused(const float* __restrict__ t,
                                                    const float* __restrict__ cp,
                                                    float* __restrict__ out, int n) {
    __shared__ float sbc[2 * D_MODEL];

    const int tid = threadIdx.x;
    if (tid < D_MODEL) {
        float v0 = cp[tid];            // cp[0][d]
        float B = v0, C = -v0;
        for (int i = 1; i < NUM_CP - 1; ++i) {
            float v = cp[i * D_MODEL + tid];
            B = fmaf(1.0f - (float)i, v, B);
            C += v;
        }
        sbc[tid] = B;
        sbc[D_MODEL + tid] = C;
    }
    __syncthreads();

    const int lane = tid & 63;
    const int c    = lane & 31;        // float4 column (0..31) -> dims 4c..4c+3
    const int half = lane >> 5;        // 0: even row of pair, 1: odd row

    const f32x4 b  = reinterpret_cast<const f32x4*>(sbc)[c];
    const f32x4 cv = reinterpret_cast<const f32x4*>(sbc + D_MODEL)[c];

    const int waveGlobal = blockIdx.x * 4 + (tid >> 6);
    const int nWaves     = gridDim.x * 4;
    const int rowStride  = nWaves * 8;
    f32x4* __restrict__ outq = reinterpret_cast<f32x4*>(out);

    int R0 = waveGlobal * 8;
    if (R0 >= n) return;

    bool full = (R0 + 7 < n);
    f32x4 ta, tb;                      // t[R0..R0+3], t[R0+4..R0+7] (broadcast)
    if (full) {
        ta = *reinterpret_cast<const f32x4*>(t + R0);
        tb = *reinterpret_cast<const f32x4*>(t + R0 + 4);
    }

    for (; R0 < n; R0 += rowStride) {
        const int R0n = R0 + rowStride;
        const bool fulln = (R0n + 7 < n);
        f32x4 tan_, tbn;
        if (fulln) {                   // prefetch next iter BEFORE stores
            tan_ = *reinterpret_cast<const f32x4*>(t + R0n);
            tbn  = *reinterpret_cast<const f32x4*>(t + R0n + 4);
        }

        if (full) {
            // this thread's rows: R0 + 2k + half, k = 0..3
            float tv[4];
            tv[0] = half ? ta.y : ta.x;
            tv[1] = half ? ta.w : ta.z;
            tv[2] = half ? tb.y : tb.x;
            tv[3] = half ? tb.w : tb.z;
#pragma unroll
            for (int k = 0; k < 4; ++k) tv[k] = fminf(fmaxf(tv[k], 0.0f), 1.0f);
#pragma unroll
            for (int k = 0; k < 4; ++k) {
                f32x4 o;
                o.x = fmaf(tv[k], cv.x, b.x);
                o.y = fmaf(tv[k], cv.y, b.y);
                o.z = fmaf(tv[k], cv.z, b.z);
                o.w = fmaf(tv[k], cv.w, b.w);
                // rows (R0+2k) and (R0+2k+1): lane l -> base + l*16, 1 KB contiguous
                __builtin_nontemporal_store(o, &outq[(R0 + 2 * k + half) * 32 + c]);
            }
        } else {
            for (int k = 0; k < 4; ++k) {
                const int r = R0 + 2 * k + half;
                if (r < n) {
                    float tv = fminf(fmaxf(t[r], 0.0f), 1.0f);
                    f32x4 o;
                    o.x = fmaf(tv, cv.x, b.x);
                    o.y = fmaf(tv, cv.y, b.y);
                    o.z = fmaf(tv, cv.z, b.z);
                    o.w = fmaf(tv, cv.w, b.w);
                    __builtin_nontemporal_store(o, &outq[r * 32 + c]);
                }
            }
        }
        ta = tan_;
        tb = tbn;
        full = fulln;
    }
}

extern "C" void kernel_launch(void* const* d_in, const int* in_sizes, int n_in,
                              void* d_out, int out_size, void* d_ws, size_t ws_size,
                              hipStream_t stream) {
    const float* t  = (const float*)d_in[0];
    const float* cp = (const float*)d_in[1];
    float* out = (float*)d_out;
    const int n = in_sizes[0];

    // 2048 blocks x 256 threads = 8 blocks/CU -> full 32-wave occupancy.
    const int waveTasks  = (n + 7) / 8;          // 8 rows per wave-iter
    const int wantBlocks = (waveTasks + 3) / 4;  // 4 waves per block
    const int blocks = wantBlocks < 2048 ? wantBlocks : 2048;
    spline_fused<<<blocks, 256, 0, stream>>>(t, cp, out, n);
}